// Round 5
// baseline (357.895 us; speedup 1.0000x reference)
//
#include <hip/hip_runtime.h>
#include <stdint.h>

// Layered Bayesian net marginal chain: 63 sequential layers, M=16384 nodes,
// K=4 parents, C=16 CPT entries per node.
//
// R3 -> R4: per-layer cost (3.87us) = ~4 irreducible L3 round trips for the
// device-wide barrier (store-drain, arrive, detect, gather). Halve the
// barrier count: fuse layer pairs. Thread m computes row r+1 by redundantly
// recomputing its 4 parents' row-r values from row r-1 (6 node-evals,
// 20 marginal gathers). All STATIC work (parent idx/logit gathers, 96
// sigmoids) runs inside the spin window; only p/q combines follow the
// barrier. Own-idx for the next pair prefetched one barrier early so the
// dependent static chain starts at arrive. 32 barriers instead of 63.
// Barrier stays fence-free: relaxed agent atomics (write-through / L2-bypass,
// coherent at L3) + s_waitcnt vmcnt(0) drain before per-wave arrival.

namespace {
constexpr int kLayers  = 63;     // hidden layers
constexpr int kM       = 16384;  // nodes per layer
constexpr int kBlocks  = 64;
constexpr int kThreads = 256;    // kBlocks*kThreads == kM, 1 thread per node
constexpr int kPairs   = 31;     // layers 0..61 fused in pairs; layer 62 single
constexpr int kNumBars = kPairs + 1;              // 32
constexpr unsigned kBarStride = 16;               // uint32 per slot = 64B line
constexpr unsigned kBarTarget = kBlocks * (kThreads / 64);  // per-WAVE arrivals
}

__global__ void zero_bars_kernel(uint32_t* __restrict__ bar, int n) {
  int i = blockIdx.x * blockDim.x + threadIdx.x;
  if (i < n) bar[i] = 0u;
}

__device__ __forceinline__ float fsig(float x) {
  // sigmoid; fp32 fast-math is far inside the 1.8e-2 abs threshold
  return __fdividef(1.0f, 1.0f + __expf(-x));
}

// Agent-scope (device-coherent) accesses: bypass the non-coherent per-XCD
// L1/L2, hit the coherence point directly. No cache-wide maintenance.
__device__ __forceinline__ void agent_store(float* p, float v) {
  __hip_atomic_store(p, v, __ATOMIC_RELAXED, __HIP_MEMORY_SCOPE_AGENT);
}
__device__ __forceinline__ float agent_load(const float* p) {
  return __hip_atomic_load(p, __ATOMIC_RELAXED, __HIP_MEMORY_SCOPE_AGENT);
}
__device__ __forceinline__ uint32_t bar_load(const uint32_t* p) {
  return __hip_atomic_load(p, __ATOMIC_RELAXED, __HIP_MEMORY_SCOPE_AGENT);
}

// weight[c] factorizes over parents (MSB-first bit order, matches _configs):
// c = b0 b1 b2 b3, fk(1)=pk, fk(0)=1-pk.
__device__ __forceinline__ float combine16(const float* s,
                                           float p0, float p1, float p2, float p3) {
  float q0 = 1.0f - p0, q1 = 1.0f - p1, q2 = 1.0f - p2, q3 = 1.0f - p3;
  float w0 = q2 * q3, w1 = q2 * p3, w2 = p2 * q3, w3 = p2 * p3;   // (b2,b3)
  float i0 = s[0]  * w0 + s[1]  * w1 + s[2]  * w2 + s[3]  * w3;   // (b0,b1)=(0,0)
  float i1 = s[4]  * w0 + s[5]  * w1 + s[6]  * w2 + s[7]  * w3;   // (0,1)
  float i2 = s[8]  * w0 + s[9]  * w1 + s[10] * w2 + s[11] * w3;   // (1,0)
  float i3 = s[12] * w0 + s[13] * w1 + s[14] * w2 + s[15] * w3;   // (1,1)
  return (q0 * q1) * i0 + (q0 * p1) * i1 + (p0 * q1) * i2 + (p0 * p1) * i3;
}

#define SIG16(S, V0, V1, V2, V3)                                              \
  S[0]  = fsig((V0).x); S[1]  = fsig((V0).y); S[2]  = fsig((V0).z); S[3]  = fsig((V0).w); \
  S[4]  = fsig((V1).x); S[5]  = fsig((V1).y); S[6]  = fsig((V1).z); S[7]  = fsig((V1).w); \
  S[8]  = fsig((V2).x); S[9]  = fsig((V2).y); S[10] = fsig((V2).z); S[11] = fsig((V2).w); \
  S[12] = fsig((V3).x); S[13] = fsig((V3).y); S[14] = fsig((V3).z); S[15] = fsig((V3).w)

__global__ __launch_bounds__(kThreads, 1) void bayes_chain_kernel(
    const float* __restrict__ root_logits,   // [kM]
    const float* __restrict__ layer_logits,  // [kLayers][kM][16]
    const int*   __restrict__ parent_idx,    // [kLayers][kM][4]
    float* __restrict__ out,                 // [kLayers+1][kM]
    uint32_t* __restrict__ bar)              // [kNumBars][kBarStride]
{
  const int m = blockIdx.x * kThreads + threadIdx.x;

  // ---- row 0: root marginals (write-through so consumers can gather) ----
  agent_store(&out[m], fsig(root_logits[m]));

  const int4*   pidx = reinterpret_cast<const int4*>(parent_idx);  // [63][M]
  const float4* lg   = reinterpret_cast<const float4*>(layer_logits); // [63][M][4]

  // own parent-idx for the first pair, prefetched before the first barrier
  int4 idxA = pidx[(size_t)0 * kM + m];   // idx[layer0][m] -> row1's parents
  int4 idxB = pidx[(size_t)1 * kM + m];   // idx[layer1][m] -> row2's parents

  for (int pair = 0; pair < kPairs; ++pair) {
    const int tA = 2 * pair;        // layer producing row tA+1
    const int tB = tA + 1;          // layer producing row tA+2
    const float* prevRow = out + (size_t)tA * kM;        // gather source: row tA
    float* rowA = out + (size_t)(tA + 1) * kM;
    float* rowB = out + (size_t)(tA + 2) * kM;

    // ============ arrive at barrier `pair` (fence-free) ============
    // Drain this wave's write-through stores: acked => at coherence point;
    // the arrive-add issued after cannot be observed before the data.
    asm volatile("s_waitcnt vmcnt(0)" ::: "memory");
    __builtin_amdgcn_sched_barrier(0);
    if ((threadIdx.x & 63) == 0) {
      __hip_atomic_fetch_add(&bar[pair * kBarStride], 1u,
                             __ATOMIC_RELAXED, __HIP_MEMORY_SCOPE_AGENT);
    }

    // ============ static prefetch + sigmoid precompute (spin window) =====
    const size_t bA = (size_t)tA * kM;
    const size_t bB = (size_t)tB * kM;
    // own logits, both layers (coalesced)
    float4 la0 = lg[(bA + m) * 4 + 0], la1 = lg[(bA + m) * 4 + 1];
    float4 la2 = lg[(bA + m) * 4 + 2], la3 = lg[(bA + m) * 4 + 3];
    float4 lb0 = lg[(bB + m) * 4 + 0], lb1 = lg[(bB + m) * 4 + 1];
    float4 lb2 = lg[(bB + m) * 4 + 2], lb3 = lg[(bB + m) * 4 + 3];
    // rowB's parents live in layer tA: gather their idx + logits (static)
    const int p0i = idxB.x, p1i = idxB.y, p2i = idxB.z, p3i = idxB.w;
    int4 gpi0 = pidx[bA + p0i];
    int4 gpi1 = pidx[bA + p1i];
    int4 gpi2 = pidx[bA + p2i];
    int4 gpi3 = pidx[bA + p3i];
    float4 pl00 = lg[(bA + p0i) * 4 + 0], pl01 = lg[(bA + p0i) * 4 + 1];
    float4 pl02 = lg[(bA + p0i) * 4 + 2], pl03 = lg[(bA + p0i) * 4 + 3];
    float4 pl10 = lg[(bA + p1i) * 4 + 0], pl11 = lg[(bA + p1i) * 4 + 1];
    float4 pl12 = lg[(bA + p1i) * 4 + 2], pl13 = lg[(bA + p1i) * 4 + 3];
    float4 pl20 = lg[(bA + p2i) * 4 + 0], pl21 = lg[(bA + p2i) * 4 + 1];
    float4 pl22 = lg[(bA + p2i) * 4 + 2], pl23 = lg[(bA + p2i) * 4 + 3];
    float4 pl30 = lg[(bA + p3i) * 4 + 0], pl31 = lg[(bA + p3i) * 4 + 1];
    float4 pl32 = lg[(bA + p3i) * 4 + 2], pl33 = lg[(bA + p3i) * 4 + 3];
    // next pair's own idx, one barrier early (breaks the dependent chain)
    const int tAn = tA + 2;
    const int tBn = (tB + 2 <= kLayers - 1) ? tB + 2 : kLayers - 1;
    int4 idxAn = pidx[(size_t)tAn * kM + m];
    int4 idxBn = pidx[(size_t)tBn * kM + m];

    // all sigmoids are static -> burn them in the spin window
    float sA[16];  SIG16(sA, la0, la1, la2, la3);
    float sB[16];  SIG16(sB, lb0, lb1, lb2, lb3);
    float sP0[16]; SIG16(sP0, pl00, pl01, pl02, pl03);
    float sP1[16]; SIG16(sP1, pl10, pl11, pl12, pl13);
    float sP2[16]; SIG16(sP2, pl20, pl21, pl22, pl23);
    float sP3[16]; SIG16(sP3, pl30, pl31, pl32, pl33);

    // ============ wait for all 256 wave arrivals ============
    while (bar_load(&bar[pair * kBarStride]) < kBarTarget) {
      __builtin_amdgcn_s_sleep(1);
    }
    asm volatile("" ::: "memory");
    __builtin_amdgcn_sched_barrier(0);

    // ============ barrier-dependent: gather row tA, combine ============
    float gA0 = agent_load(&prevRow[idxA.x]);
    float gA1 = agent_load(&prevRow[idxA.y]);
    float gA2 = agent_load(&prevRow[idxA.z]);
    float gA3 = agent_load(&prevRow[idxA.w]);
    float g00 = agent_load(&prevRow[gpi0.x]), g01 = agent_load(&prevRow[gpi0.y]);
    float g02 = agent_load(&prevRow[gpi0.z]), g03 = agent_load(&prevRow[gpi0.w]);
    float g10 = agent_load(&prevRow[gpi1.x]), g11 = agent_load(&prevRow[gpi1.y]);
    float g12 = agent_load(&prevRow[gpi1.z]), g13 = agent_load(&prevRow[gpi1.w]);
    float g20 = agent_load(&prevRow[gpi2.x]), g21 = agent_load(&prevRow[gpi2.y]);
    float g22 = agent_load(&prevRow[gpi2.z]), g23 = agent_load(&prevRow[gpi2.w]);
    float g30 = agent_load(&prevRow[gpi3.x]), g31 = agent_load(&prevRow[gpi3.y]);
    float g32 = agent_load(&prevRow[gpi3.z]), g33 = agent_load(&prevRow[gpi3.w]);

    // own row-A value: store ASAP (gets the write-through in flight early)
    agent_store(&rowA[m], combine16(sA, gA0, gA1, gA2, gA3));

    // recompute rowB's 4 parents (row tA+1 values), then rowB
    float pv0 = combine16(sP0, g00, g01, g02, g03);
    float pv1 = combine16(sP1, g10, g11, g12, g13);
    float pv2 = combine16(sP2, g20, g21, g22, g23);
    float pv3 = combine16(sP3, g30, g31, g32, g33);
    agent_store(&rowB[m], combine16(sB, pv0, pv1, pv2, pv3));

    idxA = idxAn;
    idxB = idxBn;
  }

  // ---- final single layer t=62 (row 63); idxA == idx[62][m] ----
  {
    const int t = kLayers - 1;
    const float* prevRow = out + (size_t)t * kM;
    float* row = out + (size_t)(t + 1) * kM;

    asm volatile("s_waitcnt vmcnt(0)" ::: "memory");
    __builtin_amdgcn_sched_barrier(0);
    if ((threadIdx.x & 63) == 0) {
      __hip_atomic_fetch_add(&bar[kPairs * kBarStride], 1u,
                             __ATOMIC_RELAXED, __HIP_MEMORY_SCOPE_AGENT);
    }
    const size_t b = (size_t)t * kM;
    float4 l0 = lg[(b + m) * 4 + 0], l1 = lg[(b + m) * 4 + 1];
    float4 l2 = lg[(b + m) * 4 + 2], l3 = lg[(b + m) * 4 + 3];
    float s[16]; SIG16(s, l0, l1, l2, l3);

    while (bar_load(&bar[kPairs * kBarStride]) < kBarTarget) {
      __builtin_amdgcn_s_sleep(1);
    }
    asm volatile("" ::: "memory");
    __builtin_amdgcn_sched_barrier(0);

    float g0 = agent_load(&prevRow[idxA.x]);
    float g1 = agent_load(&prevRow[idxA.y]);
    float g2 = agent_load(&prevRow[idxA.z]);
    float g3 = agent_load(&prevRow[idxA.w]);
    agent_store(&row[m], combine16(s, g0, g1, g2, g3));
  }
}

extern "C" void kernel_launch(void* const* d_in, const int* in_sizes, int n_in,
                              void* d_out, int out_size, void* d_ws, size_t ws_size,
                              hipStream_t stream) {
  const float* root = (const float*)d_in[0];
  const float* lg   = (const float*)d_in[1];
  const int*   pidx = (const int*)d_in[2];
  float* out        = (float*)d_out;
  uint32_t* bar     = (uint32_t*)d_ws;   // 32 * 64B = 2KB of scratch

  // Zero barrier counters every launch (d_ws is poisoned once, never
  // re-poisoned between graph replays -> must re-init ourselves).
  const int nbar = kNumBars * (int)kBarStride;
  zero_bars_kernel<<<(nbar + 255) / 256, 256, 0, stream>>>(bar, nbar);

  bayes_chain_kernel<<<kBlocks, kThreads, 0, stream>>>(root, lg, pidx, out, bar);
}

// Round 6
// 134.014 us; speedup vs baseline: 2.6706x; 2.6706x over previous
//
#include <hip/hip_runtime.h>
#include <stdint.h>

// Layered Bayesian net marginal chain: 63 sequential layers, M=16384 nodes,
// K=4 parents, C=16 CPT entries per node.
//
// R4 post-mortem: pair-fusion regressed (FETCH 57->146MB; the redundant
// parent gathers are uncoalesced scatter that outgrew the spin window).
//
// R5: eliminate the device-wide barrier entirely -> fine-grained dataflow.
// Marginals are strictly positive, so the DATA is its own ready-flag:
//   - every launch, re-init all output rows to sentinel -1.0f (init kernel;
//     kernel-end writeback makes it globally visible),
//   - producers store marginals with relaxed AGENT-scope write-through
//     atomics (land at the coherence point, no fences, no drains),
//   - consumers spin on their own 4 parent locations with relaxed
//     AGENT-scope loads until all are >= 0.
// Per-layer critical path drops from 4 L3 round-trips (counter barrier:
// drain + arrive + detect + gather) to ~2 (store visibility + poll detect),
// and each wave waits only on the waves producing its ~256 parents, not on
// all 16384 nodes. No ordering hazards: flag == data, single location.
// Deadlock-free: all 256 blocks co-resident (1 wave/CU), layer DAG acyclic.
// Static inputs (own logits+idx, coalesced) prefetch one layer ahead;
// sigmoids precompute before the poll; only the ~30-op combine + store
// follow parent arrival.

namespace {
constexpr int kLayers  = 63;      // hidden layers
constexpr int kM       = 16384;   // nodes per layer
constexpr int kBlocks  = 256;     // 1 block (1 wave) per CU
constexpr int kThreads = 64;      // kBlocks*kThreads == kM, 1 thread per node
constexpr float kSentinel = -1.0f;
}

// Re-init the whole out buffer (rows 0..63) to sentinel each launch.
// Normal cached stores; the implicit kernel-end cache writeback makes them
// visible to the chain kernel's agent-scope loads.
__global__ void init_sentinel_kernel(float4* __restrict__ out4) {
  int i = blockIdx.x * blockDim.x + threadIdx.x;   // 262144 float4 total
  out4[i] = make_float4(kSentinel, kSentinel, kSentinel, kSentinel);
}

__device__ __forceinline__ float fsig(float x) {
  // sigmoid; fp32 fast-math is far inside the 1.8e-2 abs threshold
  return __fdividef(1.0f, 1.0f + __expf(-x));
}

// Agent-scope (device-coherent) accesses: bypass the non-coherent per-XCD
// L1/L2, hit the coherence point directly. No cache-wide maintenance.
__device__ __forceinline__ void agent_store(float* p, float v) {
  __hip_atomic_store(p, v, __ATOMIC_RELAXED, __HIP_MEMORY_SCOPE_AGENT);
}
__device__ __forceinline__ float agent_load(const float* p) {
  return __hip_atomic_load(p, __ATOMIC_RELAXED, __HIP_MEMORY_SCOPE_AGENT);
}

// weight[c] factorizes over parents (MSB-first bit order, matches _configs):
// c = b0 b1 b2 b3, fk(1)=pk, fk(0)=1-pk.
__device__ __forceinline__ float combine16(const float* s,
                                           float p0, float p1, float p2, float p3) {
  float q0 = 1.0f - p0, q1 = 1.0f - p1, q2 = 1.0f - p2, q3 = 1.0f - p3;
  float w0 = q2 * q3, w1 = q2 * p3, w2 = p2 * q3, w3 = p2 * p3;   // (b2,b3)
  float i0 = s[0]  * w0 + s[1]  * w1 + s[2]  * w2 + s[3]  * w3;   // (b0,b1)=(0,0)
  float i1 = s[4]  * w0 + s[5]  * w1 + s[6]  * w2 + s[7]  * w3;   // (0,1)
  float i2 = s[8]  * w0 + s[9]  * w1 + s[10] * w2 + s[11] * w3;   // (1,0)
  float i3 = s[12] * w0 + s[13] * w1 + s[14] * w2 + s[15] * w3;   // (1,1)
  return (q0 * q1) * i0 + (q0 * p1) * i1 + (p0 * q1) * i2 + (p0 * p1) * i3;
}

#define SIG16(S, V0, V1, V2, V3)                                              \
  S[0]  = fsig((V0).x); S[1]  = fsig((V0).y); S[2]  = fsig((V0).z); S[3]  = fsig((V0).w); \
  S[4]  = fsig((V1).x); S[5]  = fsig((V1).y); S[6]  = fsig((V1).z); S[7]  = fsig((V1).w); \
  S[8]  = fsig((V2).x); S[9]  = fsig((V2).y); S[10] = fsig((V2).z); S[11] = fsig((V2).w); \
  S[12] = fsig((V3).x); S[13] = fsig((V3).y); S[14] = fsig((V3).z); S[15] = fsig((V3).w)

__global__ __launch_bounds__(kThreads, 1) void bayes_chain_kernel(
    const float* __restrict__ root_logits,   // [kM]
    const float* __restrict__ layer_logits,  // [kLayers][kM][16]
    const int*   __restrict__ parent_idx,    // [kLayers][kM][4]
    float* __restrict__ out)                 // [kLayers+1][kM]
{
  const int m = blockIdx.x * kThreads + threadIdx.x;

  const int4*   pidx = reinterpret_cast<const int4*>(parent_idx);     // [63][M]
  const float4* lg   = reinterpret_cast<const float4*>(layer_logits); // [63][M][4]

  // ---- row 0: root marginals, write-through so consumers' polls see them ----
  agent_store(&out[m], fsig(root_logits[m]));

  // prefetch layer 0 statics
  int4   idx = pidx[m];
  float4 l0 = lg[(size_t)m * 4 + 0], l1 = lg[(size_t)m * 4 + 1];
  float4 l2 = lg[(size_t)m * 4 + 2], l3 = lg[(size_t)m * 4 + 3];

  const float* prev = out;
  float*       cur  = out + kM;

  for (int t = 0; ; ) {
    // prefetch next layer's statics (coalesced, in flight during the poll)
    const int tn = (t + 1 < kLayers) ? t + 1 : t;   // clamp: harmless reload
    const size_t bn = (size_t)tn * kM + m;
    int4   idxn = pidx[bn];
    float4 n0 = lg[bn * 4 + 0], n1 = lg[bn * 4 + 1];
    float4 n2 = lg[bn * 4 + 2], n3 = lg[bn * 4 + 3];

    // static sigmoids for THIS layer (pure VALU, runs under the loads above)
    float s[16]; SIG16(s, l0, l1, l2, l3);

    // ---- dataflow wait: spin until all 4 parents are real values ----
    const float* a0 = &prev[idx.x];
    const float* a1 = &prev[idx.y];
    const float* a2 = &prev[idx.z];
    const float* a3 = &prev[idx.w];
    float p0, p1, p2, p3;
    for (;;) {
      p0 = agent_load(a0);
      p1 = agent_load(a1);
      p2 = agent_load(a2);
      p3 = agent_load(a3);
      if ((p0 >= 0.0f) & (p1 >= 0.0f) & (p2 >= 0.0f) & (p3 >= 0.0f)) break;
    }

    // combine + publish (write-through: this IS the ready-flag for layer t+1)
    agent_store(&cur[m], combine16(s, p0, p1, p2, p3));

    if (++t == kLayers) break;
    prev = cur;
    cur += kM;
    idx = idxn;
    l0 = n0; l1 = n1; l2 = n2; l3 = n3;
  }
}

extern "C" void kernel_launch(void* const* d_in, const int* in_sizes, int n_in,
                              void* d_out, int out_size, void* d_ws, size_t ws_size,
                              hipStream_t stream) {
  const float* root = (const float*)d_in[0];
  const float* lg   = (const float*)d_in[1];
  const int*   pidx = (const int*)d_in[2];
  float* out        = (float*)d_out;

  // (kLayers+1)*kM floats = 262144 float4 -> sentinel every launch
  // (harness memsets/poisons d_out but never between graph replays).
  init_sentinel_kernel<<<1024, 256, 0, stream>>>((float4*)out);

  bayes_chain_kernel<<<kBlocks, kThreads, 0, stream>>>(root, lg, pidx, out);
}